// Round 16
// baseline (3588.502 us; speedup 1.0000x reference)
//
#include <hip/hip_runtime.h>
#include <math.h>

// Problem constants (fixed by setup_inputs)
constexpr int B  = 8;
constexpr int D  = 512;
constexpr int T  = 4096;
constexpr int N  = 9;
constexpr int CS = 1024;
constexpr int CD = 8;

constexpr int TT   = 8;     // columns per block (8 waves x 1 col/wave)
constexpr int NBLK = 4096;

#define WN_EPS 1e-12
#define FENCE() __builtin_amdgcn_sched_barrier(0)

// ---------------- workspace layout (doubles) ----------------
// w_in_n  [N][CD][D]   : 36864
// w_out_t [N][CD][D]   : 36864   (transposed [k][d]: coalesced out-proj)
// cb_p    [N][CD][CS]  : 73728   (PLANAR [k][c]: global_load_lds staging src)
// cb_sq   [N][CS]      : 9216
// loss partials at ws+160000 : NBLK doubles

__global__ void rvq_prep(const float* __restrict__ in_v,
                         const float* __restrict__ in_g,
                         const float* __restrict__ out_v,
                         const float* __restrict__ out_g,
                         const float* __restrict__ cb,
                         double* __restrict__ ws) {
    double* w_in_n  = ws;
    double* w_out_t = ws + N * CD * D;
    double* cb_p    = ws + 2 * N * CD * D;
    double* cb_sq   = cb_p + N * CD * CS;

    int blk = blockIdx.x;
    int tid = threadIdx.x;

    if (blk == 0) {
        int row = tid;                       // 72 rows of length 512
        if (row < N * CD) {
            const float* v = in_v + (size_t)row * D;
            double s = 0.0;
            for (int j = 0; j < D; ++j) { double x = (double)v[j]; s += x * x; }
            double denom = fmax(sqrt(s), WN_EPS);
            double g = (double)in_g[row];
            for (int j = 0; j < D; ++j)
                w_in_n[(size_t)row * D + j] = (g * (double)v[j]) / denom;
        }
    } else if (blk <= 18) {
        int row = (blk - 1) * 256 + tid;     // 4608 rows (i,d) of length 8
        if (row < N * D) {
            const float* v = out_v + (size_t)row * CD;
            int i = row / D, d = row % D;
            double s = 0.0;
            #pragma unroll
            for (int k = 0; k < CD; ++k) { double x = (double)v[k]; s += x * x; }
            double denom = fmax(sqrt(s), WN_EPS);
            double g = (double)out_g[row];
            #pragma unroll
            for (int k = 0; k < CD; ++k)
                w_out_t[((size_t)i * CD + k) * D + d] = (g * (double)v[k]) / denom;
        }
    } else {
        int row = (blk - 19) * 256 + tid;    // 9216 rows (i,c) of length 8
        if (row < N * CS) {
            const float* v = cb + (size_t)row * CD;
            int i = row / CS, c = row % CS;
            double s = 0.0;
            #pragma unroll
            for (int k = 0; k < CD; ++k) { double x = (double)v[k]; s += x * x; }
            double denom = fmax(sqrt(s), WN_EPS);
            double sq = 0.0;
            #pragma unroll
            for (int k = 0; k < CD; ++k) {
                double e = (double)v[k] / denom;
                cb_p[((size_t)i * CD + k) * CS + c] = e;   // planar [k][c]
                sq += e * e;
            }
            cb_sq[row] = sq;
        }
    }
}

// ---- cross-lane helpers (wave64); CTRL must be a literal ----
template<int CTRL>
__device__ inline double dpp_mov_f64(double x) {
    union { double d; int i[2]; } u, v;
    u.d = x;
    v.i[0] = __builtin_amdgcn_update_dpp(0, u.i[0], CTRL, 0xF, 0xF, false);
    v.i[1] = __builtin_amdgcn_update_dpp(0, u.i[1], CTRL, 0xF, 0xF, false);
    return v.d;
}
template<int CTRL>
__device__ inline int dpp_mov_i32(int x) {
    return __builtin_amdgcn_update_dpp(0, x, CTRL, 0xF, 0xF, false);
}
__device__ inline double wave_allsum_f64(double x) {
    x += dpp_mov_f64<0xB1>(x);   // quad_perm(1,0,3,2)
    x += dpp_mov_f64<0x4E>(x);   // quad_perm(2,3,0,1)
    x += dpp_mov_f64<0x141>(x);  // row_half_mirror
    x += dpp_mov_f64<0x140>(x);  // row_mirror
    x += __shfl_xor(x, 16, 64);
    x += __shfl_xor(x, 32, 64);
    return x;
}
template<int CTRL>
__device__ inline void argmin_round_dpp(double& bd, int& bi) {
    double od = dpp_mov_f64<CTRL>(bd);
    int    oi = dpp_mov_i32<CTRL>(bi);
    bool t = (od < bd) || (od == bd && oi < bi);
    bd = t ? od : bd;
    bi = t ? oi : bi;
}
__device__ inline void argmin_round_shfl(double& bd, int& bi, int off) {
    double od = __shfl_xor(bd, off, 64);
    int    oi = __shfl_xor(bi, off, 64);
    bool t = (od < bd) || (od == bd && oi < bi);
    bd = t ? od : bd;
    bi = t ? oi : bi;
}

// async global -> LDS, 16B per lane (HW writes lds_base + lane*16)
__device__ inline void gload16(const double* g, double* l3) {
    __builtin_amdgcn_global_load_lds(
        (const __attribute__((address_space(1))) void*)g,
        (__attribute__((address_space(3))) void*)l3, 16, 0, 0);
}

__global__ __launch_bounds__(512)
void rvq_main(const float* __restrict__ z,
              const float* __restrict__ in_b,
              const float* __restrict__ out_b,
              const float* __restrict__ cb,
              const double* __restrict__ ws,
              double* __restrict__ wsl,
              float* __restrict__ out) {
    const double* w_in_n  = ws;
    const double* w_out_t = ws + N * CD * D;
    const double* cb_p    = ws + 2 * N * CD * D;
    const double* cb_sq   = cb_p + N * CD * CS;

    extern __shared__ char lds[];            // 32832 B dynamic
    double* bufA = (double*)lds;             // 16 KB quarter buffer ([k][256] planar)
    double* bufB = bufA + 2048;              // 16 KB
    double* wl   = (double*)(lds + 32768);   // 8 loss slots
    float*  zt   = (float*)lds;              // transpose overlay (prologue/epilogue only)

    const int tid = threadIdx.x;             // 512 threads = 8 waves
    const int l   = tid & 63;
    const int w   = __builtin_amdgcn_readfirstlane(tid >> 6);
    const int blk = blockIdx.x;              // 4096
    const int b   = blk >> 9;                // 512 blocks per batch
    const int t0  = (blk & 511) * TT;
    const int tc  = t0 + w;                  // this wave's column

    double r[8];                             // residual: d = l + 64*j

    // ---- transpose z in four d-quarters (all r indices compile-time) ----
    {
        const float* zb = z + (size_t)b * D * T + t0;
        #pragma unroll
        for (int dq = 0; dq < 4; ++dq) {
            __syncthreads();
            #pragma unroll
            for (int rr = 0; rr < 2; ++rr) {
                int e = rr * 512 + tid;
                int d = e >> 3, c = e & 7;
                zt[d * 9 + c] = zb[(size_t)(d + 128 * dq) * T + c];
            }
            __syncthreads();
            #pragma unroll
            for (int jj = 0; jj < 2; ++jj)
                r[2 * dq + jj] = (double)zt[(l + 64 * jj) * 9 + w];
        }
    }
    __syncthreads();   // zt dead; lds becomes codebook quarter buffers

    double ze[CD];
    double wloss = 0.0;

    float* codes_out = out + (size_t)B * D * T;
    float* lat_out   = codes_out + (size_t)B * N * T;

    // stage a codebook quarter: wave w loads plane k=w (256 doubles) via 2x1KB
    #define ISSUE_Q(BUF, I, Q)  {                                              \
        const double* _src = cb_p + ((size_t)(I) * CD + w) * CS + (Q) * 256;   \
        gload16(_src + l * 2,       (BUF) + w * 256);                          \
        gload16(_src + 128 + l * 2, (BUF) + w * 256 + 128);                    \
    }

    #define SCAN_Q(BUF, Q) {                                                   \
        _Pragma("unroll")                                                      \
        for (int g = 0; g < 4; ++g) {                                          \
            int cl = l + 64 * g;                                               \
            double dot = 0.0;                                                  \
            _Pragma("unroll")                                                  \
            for (int k = 0; k < CD; ++k)                                       \
                dot = fma(ze[k], (BUF)[k * 256 + cl], dot);                    \
            int c = (Q) * 256 + cl;                                            \
            double dist = fma(m2i, dot, es) + Cq[c];                           \
            bool take = (dist < best);      /* strict <: first-min wins */     \
            best  = take ? dist : best;                                        \
            bcode = take ? c : bcode;                                          \
        }                                                                      \
    }

    #pragma unroll 1
    for (int i = 0; i < N; ++i) {
        // ---- issue quarter 0 (hides under in-proj) ----
        ISSUE_Q(bufA, i, 0);

        // ---- in-proj: ze[k] = sum_d w_in[k][d] * r[d] + bias ----
        const double* Wi = w_in_n + (size_t)i * CD * D;
        #pragma unroll 2
        for (int k = 0; k < CD; ++k) {
            const double* wk = Wi + (size_t)k * D + l;
            double p = 0.0;
            #pragma unroll
            for (int j = 0; j < 8; ++j)
                p = fma(wk[64 * j], r[j], p);
            ze[k] = wave_allsum_f64(p) + (double)in_b[i * CD + k];
        }
        FENCE();

        // ---- latents (lane 0 of each wave: 8 scalar f32 stores) ----
        if (l == 0) {
            #pragma unroll
            for (int k = 0; k < CD; ++k)
                lat_out[((size_t)b * N * CD + (size_t)i * CD + k) * T + tc] = (float)ze[k];
        }

        // ---- normalize constants ----
        double es, m2i;
        {
            double s = 0.0;
            #pragma unroll
            for (int k = 0; k < CD; ++k) s = fma(ze[k], ze[k], s);
            double denom = fmax(sqrt(s), WN_EPS);
            double inv = 1.0 / denom;
            es  = s * inv * inv;
            m2i = -2.0 * inv;
        }
        FENCE();

        // ---- quarter-pipelined LDS scan (double-buffered) ----
        const double* Cq = cb_sq + (size_t)i * CS;
        double best = __builtin_inf();
        int    bcode = 0;

        __syncthreads();            // q0 arrived; bufB free (prev q3 scanned)
        ISSUE_Q(bufB, i, 1);
        SCAN_Q(bufA, 0);
        __syncthreads();            // q1 arrived; bufA free
        ISSUE_Q(bufA, i, 2);
        SCAN_Q(bufB, 1);
        __syncthreads();            // q2 arrived; bufB free
        ISSUE_Q(bufB, i, 3);
        SCAN_Q(bufA, 2);
        __syncthreads();            // q3 arrived
        SCAN_Q(bufB, 3);
        FENCE();

        // ---- argmin butterfly across 64 lanes (first-min tie-break) ----
        argmin_round_dpp<0xB1>(best, bcode);
        argmin_round_dpp<0x4E>(best, bcode);
        argmin_round_dpp<0x141>(best, bcode);
        argmin_round_dpp<0x140>(best, bcode);
        argmin_round_shfl(best, bcode, 16);
        argmin_round_shfl(best, bcode, 32);
        FENCE();

        // ---- code (lane 0 scalar store) ----
        if (l == 0)
            codes_out[((size_t)b * N + i) * T + tc] = (float)bcode;

        // ---- gather raw code + loss + straight-through (q overwrites ze) ----
        {
            int ui = __builtin_amdgcn_readfirstlane(bcode);
            const float* crow = cb + (size_t)i * CS * CD + (size_t)ui * CD;
            #pragma unroll
            for (int k = 0; k < CD; ++k) {
                double cv = (double)crow[k];
                double zv = ze[k];
                double df = zv - cv;
                wloss = fma(df, df, wloss);
                ze[k] = zv + (cv - zv);    // z_e + (z_q_i - z_e)
            }
        }
        FENCE();

        // ---- out-proj (transposed weights: coalesced) + residual update ----
        const double* Wo = w_out_t + (size_t)i * CD * D;
        #pragma unroll 1
        for (int j = 0; j < 8; ++j) {
            int d = l + 64 * j;
            double o = 0.0;
            #pragma unroll
            for (int k = 0; k < CD; ++k)
                o = fma(Wo[(size_t)k * D + d], ze[k], o);
            o += (double)out_b[i * D + d];
            r[j] -= o;
        }
        FENCE();
        // next iteration issues q0 -> bufA immediately (bufA's q2 already
        // scanned by all waves before the q3-top barrier): safe, and the
        // loads hide under next stage's in-proj.
    }

    // ---- final: z_q = z - r, four d-quarters (static indices) ----
    {
        const float* zb = z + (size_t)b * D * T + t0;
        float* ob = out + (size_t)b * D * T + t0;
        #pragma unroll
        for (int dq = 0; dq < 4; ++dq) {
            __syncthreads();
            #pragma unroll
            for (int jj = 0; jj < 2; ++jj)
                zt[(l + 64 * jj) * 9 + w] = (float)r[2 * dq + jj];
            __syncthreads();
            #pragma unroll
            for (int rr = 0; rr < 2; ++rr) {
                int e = rr * 512 + tid;
                int d = e >> 3, c = e & 7;
                size_t off = (size_t)(d + 128 * dq) * T + c;
                ob[off] = zb[off] - zt[d * 9 + c];
            }
        }
    }

    // ---- per-block loss partial (wloss is wave-uniform) ----
    __syncthreads();
    if (l == 0) wl[w] = wloss;
    __syncthreads();
    if (tid == 0) {
        double s = 0.0;
        #pragma unroll
        for (int ww = 0; ww < 8; ++ww) s += wl[ww];
        wsl[blk] = s;
    }
}

__global__ void rvq_loss_reduce(const double* __restrict__ wsl,
                                float* __restrict__ out) {
    __shared__ double sm[4];
    int tid = threadIdx.x;
    double s = 0.0;
    for (int e = tid; e < NBLK; e += 256) s += wsl[e];
    for (int off = 32; off; off >>= 1) s += __shfl_xor(s, off, 64);
    if ((tid & 63) == 0) sm[tid >> 6] = s;
    __syncthreads();
    if (tid == 0) {
        double tot = ((sm[0] + sm[1]) + (sm[2] + sm[3])) * (1.0 / 262144.0);
        float* lossp = out + (size_t)B * D * T + (size_t)B * N * T + (size_t)B * N * CD * T;
        lossp[0] = (float)tot;   // commitment
        lossp[1] = (float)tot;   // codebook (identical in eval forward)
    }
}

extern "C" void kernel_launch(void* const* d_in, const int* in_sizes, int n_in,
                              void* d_out, int out_size, void* d_ws, size_t ws_size,
                              hipStream_t stream) {
    const float* z     = (const float*)d_in[0];
    const float* in_v  = (const float*)d_in[1];
    const float* in_g  = (const float*)d_in[2];
    const float* in_b  = (const float*)d_in[3];
    const float* out_v = (const float*)d_in[4];
    const float* out_g = (const float*)d_in[5];
    const float* out_b = (const float*)d_in[6];
    const float* cb    = (const float*)d_in[7];
    float* out  = (float*)d_out;
    double* ws  = (double*)d_ws;
    double* wsl = ws + 160000;   // loss partials

    rvq_prep<<<55, 256, 0, stream>>>(in_v, in_g, out_v, out_g, cb, ws);
    rvq_main<<<NBLK, 512, 32832, stream>>>(z, in_b, out_b, cb, ws, wsl, out);
    rvq_loss_reduce<<<1, 256, 0, stream>>>(wsl, out);
}

// Round 17
// 2707.654 us; speedup vs baseline: 1.3253x; 1.3253x over previous
//
#include <hip/hip_runtime.h>
#include <math.h>

// Problem constants (fixed by setup_inputs)
constexpr int B  = 8;
constexpr int D  = 512;
constexpr int T  = 4096;
constexpr int N  = 9;
constexpr int CS = 1024;
constexpr int CD = 8;

constexpr int TT   = 4;     // columns per block (4 waves x 1 col/wave)
constexpr int NBLK = 8192;

#define WN_EPS 1e-12
#define FENCE() __builtin_amdgcn_sched_barrier(0)

// ---------------- workspace layout (doubles) ----------------
// w_in_n  [N][CD][D]   : 36864
// w_out_t [N][CD][D]   : 36864   (transposed [k][d]: coalesced out-proj)
// cb_p    [N][CD][CS]  : 73728   (PLANAR [k][c]: global_load_lds staging src)
// cb_sq   [N][CS]      : 9216
// loss partials at ws+160000 : NBLK doubles

__global__ void rvq_prep(const float* __restrict__ in_v,
                         const float* __restrict__ in_g,
                         const float* __restrict__ out_v,
                         const float* __restrict__ out_g,
                         const float* __restrict__ cb,
                         double* __restrict__ ws) {
    double* w_in_n  = ws;
    double* w_out_t = ws + N * CD * D;
    double* cb_p    = ws + 2 * N * CD * D;
    double* cb_sq   = cb_p + N * CD * CS;

    int blk = blockIdx.x;
    int tid = threadIdx.x;

    if (blk == 0) {
        int row = tid;                       // 72 rows of length 512
        if (row < N * CD) {
            const float* v = in_v + (size_t)row * D;
            double s = 0.0;
            for (int j = 0; j < D; ++j) { double x = (double)v[j]; s += x * x; }
            double denom = fmax(sqrt(s), WN_EPS);
            double g = (double)in_g[row];
            for (int j = 0; j < D; ++j)
                w_in_n[(size_t)row * D + j] = (g * (double)v[j]) / denom;
        }
    } else if (blk <= 18) {
        int row = (blk - 1) * 256 + tid;     // 4608 rows (i,d) of length 8
        if (row < N * D) {
            const float* v = out_v + (size_t)row * CD;
            int i = row / D, d = row % D;
            double s = 0.0;
            #pragma unroll
            for (int k = 0; k < CD; ++k) { double x = (double)v[k]; s += x * x; }
            double denom = fmax(sqrt(s), WN_EPS);
            double g = (double)out_g[row];
            #pragma unroll
            for (int k = 0; k < CD; ++k)
                w_out_t[((size_t)i * CD + k) * D + d] = (g * (double)v[k]) / denom;
        }
    } else {
        int row = (blk - 19) * 256 + tid;    // 9216 rows (i,c) of length 8
        if (row < N * CS) {
            const float* v = cb + (size_t)row * CD;
            int i = row / CS, c = row % CS;
            double s = 0.0;
            #pragma unroll
            for (int k = 0; k < CD; ++k) { double x = (double)v[k]; s += x * x; }
            double denom = fmax(sqrt(s), WN_EPS);
            double sq = 0.0;
            #pragma unroll
            for (int k = 0; k < CD; ++k) {
                double e = (double)v[k] / denom;
                cb_p[((size_t)i * CD + k) * CS + c] = e;   // planar [k][c]
                sq += e * e;
            }
            cb_sq[row] = sq;
        }
    }
}

// ---- cross-lane helpers (wave64); CTRL must be a literal ----
template<int CTRL>
__device__ inline double dpp_mov_f64(double x) {
    union { double d; int i[2]; } u, v;
    u.d = x;
    v.i[0] = __builtin_amdgcn_update_dpp(0, u.i[0], CTRL, 0xF, 0xF, false);
    v.i[1] = __builtin_amdgcn_update_dpp(0, u.i[1], CTRL, 0xF, 0xF, false);
    return v.d;
}
template<int CTRL>
__device__ inline int dpp_mov_i32(int x) {
    return __builtin_amdgcn_update_dpp(0, x, CTRL, 0xF, 0xF, false);
}
__device__ inline double wave_allsum_f64(double x) {
    x += dpp_mov_f64<0xB1>(x);   // quad_perm(1,0,3,2)
    x += dpp_mov_f64<0x4E>(x);   // quad_perm(2,3,0,1)
    x += dpp_mov_f64<0x141>(x);  // row_half_mirror
    x += dpp_mov_f64<0x140>(x);  // row_mirror
    x += __shfl_xor(x, 16, 64);
    x += __shfl_xor(x, 32, 64);
    return x;
}
template<int CTRL>
__device__ inline void argmin_round_dpp(double& bd, int& bi) {
    double od = dpp_mov_f64<CTRL>(bd);
    int    oi = dpp_mov_i32<CTRL>(bi);
    bool t = (od < bd) || (od == bd && oi < bi);
    bd = t ? od : bd;
    bi = t ? oi : bi;
}
__device__ inline void argmin_round_shfl(double& bd, int& bi, int off) {
    double od = __shfl_xor(bd, off, 64);
    int    oi = __shfl_xor(bi, off, 64);
    bool t = (od < bd) || (od == bd && oi < bi);
    bd = t ? od : bd;
    bi = t ? oi : bi;
}

// async global -> LDS, 16B per lane (HW writes lds_base + lane*16)
__device__ inline void gload16(const double* g, double* l3) {
    __builtin_amdgcn_global_load_lds(
        (const __attribute__((address_space(1))) void*)g,
        (__attribute__((address_space(3))) void*)l3, 16, 0, 0);
}

__global__ __launch_bounds__(256, 4)
void rvq_main(const float* __restrict__ z,
              const float* __restrict__ in_b,
              const float* __restrict__ out_b,
              const float* __restrict__ cb,
              const double* __restrict__ ws,
              double* __restrict__ wsl,
              float* __restrict__ out) {
    const double* w_in_n  = ws;
    const double* w_out_t = ws + N * CD * D;
    const double* cb_p    = ws + 2 * N * CD * D;
    const double* cb_sq   = cb_p + N * CD * CS;

    extern __shared__ char lds[];            // 32800 B dynamic
    double* bufA = (double*)lds;             // 16 KB quarter ([k][256] planar)
    double* bufB = bufA + 2048;              // 16 KB
    double* wl   = (double*)(lds + 32768);   // 4 loss slots
    float*  zt   = (float*)lds;              // [128][5] transpose overlay (prologue/epilogue)

    const int tid = threadIdx.x;             // 256 threads = 4 waves
    const int l   = tid & 63;
    const int w   = __builtin_amdgcn_readfirstlane(tid >> 6);
    const int blk = blockIdx.x;              // 8192
    const int b   = blk >> 10;               // 1024 blocks per batch
    const int t0  = (blk & 1023) * TT;
    const int tc  = t0 + w;                  // this wave's column

    double r[8];                             // residual: d = l + 64*j

    // ---- transpose z in four d-quarters (all r indices compile-time) ----
    {
        const float* zb = z + (size_t)b * D * T + t0;
        #pragma unroll
        for (int dq = 0; dq < 4; ++dq) {
            __syncthreads();
            #pragma unroll
            for (int rr = 0; rr < 2; ++rr) {
                int e = rr * 256 + tid;
                int d = e >> 2, c = e & 3;
                zt[d * 5 + c] = zb[(size_t)(d + 128 * dq) * T + c];
            }
            __syncthreads();
            #pragma unroll
            for (int jj = 0; jj < 2; ++jj)
                r[2 * dq + jj] = (double)zt[(l + 64 * jj) * 5 + w];
        }
    }
    __syncthreads();   // zt dead; lds becomes codebook quarter buffers

    double ze[CD];
    double wloss = 0.0;

    float* codes_out = out + (size_t)B * D * T;
    float* lat_out   = codes_out + (size_t)B * N * T;

    // stage quarter Q of stage I: wave w loads planes k=2w,2w+1 (256 dbl each)
    #define ISSUE_Q(BUF, I, Q)  {                                              \
        const int _k0 = 2 * w;                                                 \
        const double* _s0 = cb_p + ((size_t)(I) * CD + _k0) * CS + (Q) * 256;  \
        gload16(_s0 + l * 2,        (BUF) + _k0 * 256);                        \
        gload16(_s0 + 128 + l * 2,  (BUF) + _k0 * 256 + 128);                  \
        const double* _s1 = _s0 + CS;                                          \
        gload16(_s1 + l * 2,        (BUF) + (_k0 + 1) * 256);                  \
        gload16(_s1 + 128 + l * 2,  (BUF) + (_k0 + 1) * 256 + 128);            \
    }

    // scan one staged quarter (streamed k: 1 live LDS value at a time)
    #define SCAN_Q(BUF, Q) {                                                   \
        _Pragma("unroll")                                                      \
        for (int g = 0; g < 4; ++g) {                                          \
            int cl = l + 64 * g;                                               \
            double dot = 0.0;                                                  \
            _Pragma("unroll")                                                  \
            for (int k = 0; k < CD; ++k)                                       \
                dot = fma(ze[k], (BUF)[k * 256 + cl], dot);                    \
            int c = (Q) * 256 + cl;                                            \
            double dist = fma(m2i, dot, es) + Cq[c];                           \
            bool take = (dist < best);      /* strict <: first-min wins */     \
            best  = take ? dist : best;                                        \
            bcode = take ? c : bcode;                                          \
        }                                                                      \
    }

    #pragma unroll 1
    for (int i = 0; i < N; ++i) {
        // ---- issue quarter 0 (latency hides under in-proj) ----
        ISSUE_Q(bufA, i, 0);

        // ---- in-proj: ze[k] = sum_d w_in[k][d] * r[d] + bias ----
        const double* Wi = w_in_n + (size_t)i * CD * D;
        #pragma unroll 2
        for (int k = 0; k < CD; ++k) {
            const double* wk = Wi + (size_t)k * D + l;
            double p = 0.0;
            #pragma unroll
            for (int j = 0; j < 8; ++j)
                p = fma(wk[64 * j], r[j], p);
            ze[k] = wave_allsum_f64(p) + (double)in_b[i * CD + k];
        }
        FENCE();

        // ---- latents (lane 0: 8 scalar f32 stores) ----
        if (l == 0) {
            #pragma unroll
            for (int k = 0; k < CD; ++k)
                lat_out[((size_t)b * N * CD + (size_t)i * CD + k) * T + tc] = (float)ze[k];
        }

        // ---- normalize constants ----
        double es, m2i;
        {
            double s = 0.0;
            #pragma unroll
            for (int k = 0; k < CD; ++k) s = fma(ze[k], ze[k], s);
            double denom = fmax(sqrt(s), WN_EPS);
            double inv = 1.0 / denom;
            es  = s * inv * inv;
            m2i = -2.0 * inv;
        }
        FENCE();

        // ---- quarter-pipelined LDS scan (double-buffered) ----
        const double* Cq = cb_sq + (size_t)i * CS;
        double best = __builtin_inf();
        int    bcode = 0;

        __syncthreads();            // q0 arrived; bufB free (prev q3 scanned)
        ISSUE_Q(bufB, i, 1);
        SCAN_Q(bufA, 0);
        __syncthreads();            // q1 arrived; bufA free
        ISSUE_Q(bufA, i, 2);
        SCAN_Q(bufB, 1);
        __syncthreads();            // q2 arrived; bufB free
        ISSUE_Q(bufB, i, 3);
        SCAN_Q(bufA, 2);
        __syncthreads();            // q3 arrived
        SCAN_Q(bufB, 3);
        FENCE();

        // ---- argmin butterfly across 64 lanes (first-min tie-break) ----
        argmin_round_dpp<0xB1>(best, bcode);
        argmin_round_dpp<0x4E>(best, bcode);
        argmin_round_dpp<0x141>(best, bcode);
        argmin_round_dpp<0x140>(best, bcode);
        argmin_round_shfl(best, bcode, 16);
        argmin_round_shfl(best, bcode, 32);
        FENCE();

        // ---- code (lane 0 scalar store) ----
        if (l == 0)
            codes_out[((size_t)b * N + i) * T + tc] = (float)bcode;

        // ---- gather raw code + loss + straight-through (q overwrites ze) ----
        {
            int ui = __builtin_amdgcn_readfirstlane(bcode);
            const float* crow = cb + (size_t)i * CS * CD + (size_t)ui * CD;
            #pragma unroll
            for (int k = 0; k < CD; ++k) {
                double cv = (double)crow[k];
                double zv = ze[k];
                double df = zv - cv;
                wloss = fma(df, df, wloss);
                ze[k] = zv + (cv - zv);    // z_e + (z_q_i - z_e)
            }
        }
        FENCE();

        // ---- out-proj (transposed weights: coalesced) + residual update ----
        const double* Wo = w_out_t + (size_t)i * CD * D;
        #pragma unroll 1
        for (int j = 0; j < 8; ++j) {
            int d = l + 64 * j;
            double o = 0.0;
            #pragma unroll
            for (int k = 0; k < CD; ++k)
                o = fma(Wo[(size_t)k * D + d], ze[k], o);
            o += (double)out_b[i * D + d];
            r[j] -= o;
        }
        FENCE();
        // next stage issues q0 -> bufA immediately: bufA's last read (q2 scan)
        // completed before the q3-arrival barrier -> safe.
    }

    // ---- final: z_q = z - r, four d-quarters (static indices) ----
    {
        const float* zb = z + (size_t)b * D * T + t0;
        float* ob = out + (size_t)b * D * T + t0;
        #pragma unroll
        for (int dq = 0; dq < 4; ++dq) {
            __syncthreads();
            #pragma unroll
            for (int jj = 0; jj < 2; ++jj)
                zt[(l + 64 * jj) * 5 + w] = (float)r[2 * dq + jj];
            __syncthreads();
            #pragma unroll
            for (int rr = 0; rr < 2; ++rr) {
                int e = rr * 256 + tid;
                int d = e >> 2, c = e & 3;
                size_t off = (size_t)(d + 128 * dq) * T + c;
                ob[off] = zb[off] - zt[d * 5 + c];
            }
        }
    }

    // ---- per-block loss partial (wloss is wave-uniform) ----
    __syncthreads();
    if (l == 0) wl[w] = wloss;
    __syncthreads();
    if (tid == 0) wsl[blk] = (wl[0] + wl[1]) + (wl[2] + wl[3]);
}

__global__ void rvq_loss_reduce(const double* __restrict__ wsl,
                                float* __restrict__ out) {
    __shared__ double sm[4];
    int tid = threadIdx.x;
    double s = 0.0;
    for (int e = tid; e < NBLK; e += 256) s += wsl[e];
    for (int off = 32; off; off >>= 1) s += __shfl_xor(s, off, 64);
    if ((tid & 63) == 0) sm[tid >> 6] = s;
    __syncthreads();
    if (tid == 0) {
        double tot = ((sm[0] + sm[1]) + (sm[2] + sm[3])) * (1.0 / 262144.0);
        float* lossp = out + (size_t)B * D * T + (size_t)B * N * T + (size_t)B * N * CD * T;
        lossp[0] = (float)tot;   // commitment
        lossp[1] = (float)tot;   // codebook (identical in eval forward)
    }
}

extern "C" void kernel_launch(void* const* d_in, const int* in_sizes, int n_in,
                              void* d_out, int out_size, void* d_ws, size_t ws_size,
                              hipStream_t stream) {
    const float* z     = (const float*)d_in[0];
    const float* in_v  = (const float*)d_in[1];
    const float* in_g  = (const float*)d_in[2];
    const float* in_b  = (const float*)d_in[3];
    const float* out_v = (const float*)d_in[4];
    const float* out_g = (const float*)d_in[5];
    const float* out_b = (const float*)d_in[6];
    const float* cb    = (const float*)d_in[7];
    float* out  = (float*)d_out;
    double* ws  = (double*)d_ws;
    double* wsl = ws + 160000;   // loss partials

    rvq_prep<<<55, 256, 0, stream>>>(in_v, in_g, out_v, out_g, cb, ws);
    rvq_main<<<NBLK, 256, 32800, stream>>>(z, in_b, out_b, cb, ws, wsl, out);
    rvq_loss_reduce<<<1, 256, 0, stream>>>(wsl, out);
}

// Round 18
// 1934.843 us; speedup vs baseline: 1.8547x; 1.3994x over previous
//
#include <hip/hip_runtime.h>
#include <math.h>

// Problem constants (fixed by setup_inputs)
constexpr int B  = 8;
constexpr int D  = 512;
constexpr int T  = 4096;
constexpr int N  = 9;
constexpr int CS = 1024;
constexpr int CD = 8;

constexpr int TT   = 16;   // columns per block (8 waves x 2 cols)
constexpr int CPW  = 2;
constexpr int NBLK = 2048;

#define WN_EPS 1e-12
#define SCAN_EPS 1e-3f

// ---------------- workspace layout (in doubles) ----------------
// w_in_n  [N][CD][D]   @ 0       (36864)
// w_out_t [N][CD][D]   @ 36864   (36864)  transposed [k][d]
// cb_p    [N][CD][CS]  @ 73728   (73728)  f64 planar [k][c] (verify path)
// cb_sq   [N][CS]      @ 147456  (9216)   f64 (verify path)
// cb_pf   f32[N][CD][CS] @ 156672 (36864 dbl-slots)  f32 planar (scan)
// cb_sqf  f32[N][CS]     @ 193536 (4608 dbl-slots)   f32 (scan)
// wsl     [NBLK]         @ 198144

__global__ void rvq_prep(const float* __restrict__ in_v,
                         const float* __restrict__ in_g,
                         const float* __restrict__ out_v,
                         const float* __restrict__ out_g,
                         const float* __restrict__ cb,
                         double* __restrict__ ws) {
    double* w_in_n  = ws;
    double* w_out_t = ws + 36864;
    double* cb_p    = ws + 73728;
    double* cb_sq   = ws + 147456;
    float*  cb_pf   = (float*)(ws + 156672);
    float*  cb_sqf  = (float*)(ws + 193536);

    int blk = blockIdx.x;
    int tid = threadIdx.x;

    if (blk == 0) {
        int row = tid;                       // 72 rows of length 512
        if (row < N * CD) {
            const float* v = in_v + (size_t)row * D;
            double s = 0.0;
            for (int j = 0; j < D; ++j) { double x = (double)v[j]; s += x * x; }
            double denom = fmax(sqrt(s), WN_EPS);
            double g = (double)in_g[row];
            for (int j = 0; j < D; ++j)
                w_in_n[(size_t)row * D + j] = (g * (double)v[j]) / denom;
        }
    } else if (blk <= 18) {
        int row = (blk - 1) * 256 + tid;     // 4608 rows (i,d) of length 8
        if (row < N * D) {
            const float* v = out_v + (size_t)row * CD;
            int i = row / D, d = row % D;
            double s = 0.0;
            #pragma unroll
            for (int k = 0; k < CD; ++k) { double x = (double)v[k]; s += x * x; }
            double denom = fmax(sqrt(s), WN_EPS);
            double g = (double)out_g[row];
            #pragma unroll
            for (int k = 0; k < CD; ++k)
                w_out_t[((size_t)i * CD + k) * D + d] = (g * (double)v[k]) / denom;
        }
    } else {
        int row = (blk - 19) * 256 + tid;    // 9216 rows (i,c) of length 8
        if (row < N * CS) {
            const float* v = cb + (size_t)row * CD;
            int i = row / CS, c = row % CS;
            double s = 0.0;
            #pragma unroll
            for (int k = 0; k < CD; ++k) { double x = (double)v[k]; s += x * x; }
            double denom = fmax(sqrt(s), WN_EPS);
            double sq = 0.0;
            #pragma unroll
            for (int k = 0; k < CD; ++k) {
                double e = (double)v[k] / denom;
                cb_p[((size_t)i * CD + k) * CS + c] = e;
                cb_pf[((size_t)i * CD + k) * CS + c] = (float)e;
                sq += e * e;
            }
            cb_sq[row]  = sq;
            cb_sqf[row] = (float)sq;
        }
    }
}

// ---- cross-lane helpers (wave64); CTRL must be a literal ----
template<int CTRL>
__device__ inline double dpp_mov_f64(double x) {
    union { double d; int i[2]; } u, v;
    u.d = x;
    v.i[0] = __builtin_amdgcn_update_dpp(0, u.i[0], CTRL, 0xF, 0xF, false);
    v.i[1] = __builtin_amdgcn_update_dpp(0, u.i[1], CTRL, 0xF, 0xF, false);
    return v.d;
}
template<int CTRL>
__device__ inline int dpp_mov_i32(int x) {
    return __builtin_amdgcn_update_dpp(0, x, CTRL, 0xF, 0xF, false);
}
__device__ inline double wave_allsum_f64(double x) {
    x += dpp_mov_f64<0xB1>(x);   // quad_perm(1,0,3,2)
    x += dpp_mov_f64<0x4E>(x);   // quad_perm(2,3,0,1)
    x += dpp_mov_f64<0x141>(x);  // row_half_mirror
    x += dpp_mov_f64<0x140>(x);  // row_mirror
    x += __shfl_xor(x, 16, 64);
    x += __shfl_xor(x, 32, 64);
    return x;
}
template<int CTRL>
__device__ inline void argmin_round_dpp(double& bd, int& bi) {
    double od = dpp_mov_f64<CTRL>(bd);
    int    oi = dpp_mov_i32<CTRL>(bi);
    bool t = (od < bd) || (od == bd && oi < bi);
    bd = t ? od : bd;
    bi = t ? oi : bi;
}
__device__ inline void argmin_round_shfl(double& bd, int& bi, int off) {
    double od = __shfl_xor(bd, off, 64);
    int    oi = __shfl_xor(bi, off, 64);
    bool t = (od < bd) || (od == bd && oi < bi);
    bd = t ? od : bd;
    bi = t ? oi : bi;
}

// async global -> LDS, 16B per lane (HW: lds wave-base + lane*16)
__device__ inline void gload16(const void* g, void* l3) {
    __builtin_amdgcn_global_load_lds(
        (const __attribute__((address_space(1))) void*)g,
        (__attribute__((address_space(3))) void*)l3, 16, 0, 0);
}

__global__ __launch_bounds__(512)
void rvq_main(const float* __restrict__ z,
              const float* __restrict__ in_b,
              const float* __restrict__ out_b,
              const float* __restrict__ cb,
              const double* __restrict__ ws,
              double* __restrict__ wsl,
              float* __restrict__ out) {
    const double* w_in_n  = ws;
    const double* w_out_t = ws + 36864;
    const double* cb_p    = ws + 73728;
    const double* cb_sq   = ws + 147456;
    const float*  cb_pf   = (const float*)(ws + 156672);
    const float*  cb_sqf  = (const float*)(ws + 193536);

    extern __shared__ char lds[];            // 73792 B dynamic
    float*  bufA = (float*)lds;              // 9216 f32: cb32[8][1024] + cq32[1024]
    float*  bufB = bufA + 9216;              // same
    double* wl   = (double*)(lds + 73728);   // 8 loss slots
    float*  zt   = bufB;                     // transpose overlay ([256][17] = 17.4 KB)

    const int tid = threadIdx.x;             // 512 threads = 8 waves
    const int l   = tid & 63;
    const int w   = __builtin_amdgcn_readfirstlane(tid >> 6);
    const int blk = blockIdx.x;              // 2048
    const int b   = blk >> 8;                // 256 blocks per batch
    const int t0  = (blk & 255) * TT;
    const int tw  = t0 + w * CPW;            // this wave's first column

    // stage the f32 codebook+cq image of stage I into BUF (zero VGPR cost)
    #define ISSUE(BUF, I) {                                                    \
        const float* _srcf = cb_pf + (size_t)(I) * 8192;                       \
        _Pragma("unroll")                                                      \
        for (int rr2 = 0; rr2 < 4; ++rr2)                                      \
            gload16(_srcf + rr2 * 2048 + tid * 4,                              \
                    (BUF) + rr2 * 2048 + tid * 4);                             \
        if (tid < 256)                                                         \
            gload16(cb_sqf + (size_t)(I) * 1024 + tid * 4,                     \
                    (BUF) + 8192 + tid * 4);                                   \
    }

    // ---- issue stage-0 codebook into bufA (latency hides under transpose) ----
    ISSUE(bufA, 0);

    double r[CPW][8];

    // ---- transpose z in two d-halves via zt = bufB (static r indices) ----
    {
        const float* zb = z + (size_t)b * D * T + t0;
        #pragma unroll 2
        for (int rr = 0; rr < 8; ++rr) {      // d in [0,256)
            int e = rr * 512 + tid;
            int d = e >> 4, c = e & 15;
            zt[d * 17 + c] = zb[(size_t)d * T + c];
        }
        __syncthreads();
        #pragma unroll
        for (int cc = 0; cc < CPW; ++cc)
            #pragma unroll
            for (int j = 0; j < 4; ++j)
                r[cc][j] = (double)zt[(l + 64 * j) * 17 + (w * CPW + cc)];
        __syncthreads();
        #pragma unroll 2
        for (int rr = 0; rr < 8; ++rr) {      // d in [256,512)
            int e = rr * 512 + tid;
            int d = e >> 4, c = e & 15;
            zt[d * 17 + c] = zb[(size_t)(d + 256) * T + c];
        }
        __syncthreads();
        #pragma unroll
        for (int cc = 0; cc < CPW; ++cc)
            #pragma unroll
            for (int j = 4; j < 8; ++j)
                r[cc][j] = (double)zt[(l + 64 * (j - 4)) * 17 + (w * CPW + cc)];
        __syncthreads();   // zt (bufB) free; bufA loads drained by this barrier
    }

    double ze[CD][CPW];
    double wloss = 0.0;

    float* codes_out = out + (size_t)B * D * T;
    float* lat_out   = codes_out + (size_t)B * N * T;

    #pragma unroll 1
    for (int i = 0; i < N; ++i) {
        float* bufCur = (i & 1) ? bufB : bufA;
        float* bufNxt = (i & 1) ? bufA : bufB;

        // ---- [A] issue next stage's f32 image (completes by this stage's end barrier) ----
        if (i + 1 < N) ISSUE(bufNxt, i + 1);

        // ---- [B] in-proj: ze[k][cc] = sum_d w_in[k][d]*r[d][cc] + bias (f64) ----
        const double* Wi = w_in_n + (size_t)i * CD * D;
        #pragma unroll 2
        for (int k = 0; k < CD; ++k) {
            const double* wk = Wi + (size_t)k * D + l;
            double p0 = 0.0, p1 = 0.0;
            #pragma unroll
            for (int j = 0; j < 8; ++j) {
                double wv = wk[64 * j];
                p0 = fma(wv, r[0][j], p0);
                p1 = fma(wv, r[1][j], p1);
            }
            double bias = (double)in_b[i * CD + k];
            ze[k][0] = wave_allsum_f64(p0) + bias;
            ze[k][1] = wave_allsum_f64(p1) + bias;
        }

        // ---- latents (lane 0 per wave, float2) ----
        if (l == 0) {
            #pragma unroll
            for (int k = 0; k < CD; ++k) {
                float2 v = make_float2((float)ze[k][0], (float)ze[k][1]);
                *(float2*)&lat_out[((size_t)b * N * CD + (size_t)i * CD + k) * T + tw] = v;
            }
        }

        // ---- normalize constants: f64 exact + f32 copies for the scan ----
        double es64[CPW], m2i64[CPW];
        float  es32[CPW], m2i32[CPW];
        float  za[CD], zb2[CD];
        #pragma unroll
        for (int cc = 0; cc < CPW; ++cc) {
            double s = 0.0;
            #pragma unroll
            for (int k = 0; k < CD; ++k) s = fma(ze[k][cc], ze[k][cc], s);
            double denom = fmax(sqrt(s), WN_EPS);
            double inv = 1.0 / denom;
            es64[cc]  = s * inv * inv;
            m2i64[cc] = -2.0 * inv;
            es32[cc]  = (float)es64[cc];
            m2i32[cc] = (float)m2i64[cc];
        }
        #pragma unroll
        for (int k = 0; k < CD; ++k) { za[k] = (float)ze[k][0]; zb2[k] = (float)ze[k][1]; }

        // ---- [D] f32 scan from LDS: track per-lane best AND second-best ----
        float best[CPW], second[CPW];
        int   bcode[CPW];
        #pragma unroll
        for (int cc = 0; cc < CPW; ++cc) {
            best[cc] = __builtin_inff(); second[cc] = __builtin_inff(); bcode[cc] = 0;
        }
        #pragma unroll 2
        for (int g = 0; g < 16; ++g) {
            int cl = l + 64 * g;
            float cbv[CD];
            #pragma unroll
            for (int k = 0; k < CD; ++k) cbv[k] = bufCur[k * 1024 + cl];
            float cq = bufCur[8192 + cl];
            // col 0
            {
                float dot = 0.f;
                #pragma unroll
                for (int k = 0; k < CD; ++k) dot = __builtin_fmaf(za[k], cbv[k], dot);
                float dist = __builtin_fmaf(m2i32[0], dot, es32[0]) + cq;
                if (dist < best[0]) { second[0] = best[0]; best[0] = dist; bcode[0] = cl; }
                else if (dist < second[0]) second[0] = dist;
            }
            // col 1
            {
                float dot = 0.f;
                #pragma unroll
                for (int k = 0; k < CD; ++k) dot = __builtin_fmaf(zb2[k], cbv[k], dot);
                float dist = __builtin_fmaf(m2i32[1], dot, es32[1]) + cq;
                if (dist < best[1]) { second[1] = best[1]; best[1] = dist; bcode[1] = cl; }
                else if (dist < second[1]) second[1] = dist;
            }
        }

        // ---- wave-min of f32 dist (value only) ----
        float m0 = best[0], m1 = best[1];
        #pragma unroll
        for (int off = 1; off < 64; off <<= 1) {
            m0 = fminf(m0, __shfl_xor(m0, off, 64));
            m1 = fminf(m1, __shfl_xor(m1, off, 64));
        }
        float thr0 = m0 + SCAN_EPS, thr1 = m1 + SCAN_EPS;

        // ---- exact f64 verification of candidates; wave argmin (first-min) ----
        const double* Cp64 = cb_p + (size_t)i * CD * CS;
        const double* Cq64 = cb_sq + (size_t)i * CS;
        int fcode[CPW];
        #pragma unroll
        for (int cc = 0; cc < CPW; ++cc) {
            float thr = (cc == 0) ? thr0 : thr1;
            const float* zef = (cc == 0) ? za : zb2;
            double d64 = __builtin_inf();
            int    ci  = bcode[cc];
            if (second[cc] <= thr) {
                // rare: two in-lane candidates -> full in-lane rescan, ascending c
                d64 = __builtin_inf(); ci = 0x7FFFFFFF;
                #pragma unroll 1
                for (int g = 0; g < 16; ++g) {
                    int cl = l + 64 * g;
                    float dot = 0.f;
                    #pragma unroll
                    for (int k = 0; k < CD; ++k)
                        dot = __builtin_fmaf(zef[k], bufCur[k * 1024 + cl], dot);
                    float dist = __builtin_fmaf(m2i32[cc], dot, es32[cc]) + bufCur[8192 + cl];
                    if (dist <= thr) {
                        double dd = 0.0;
                        #pragma unroll
                        for (int k = 0; k < CD; ++k)
                            dd = fma(ze[k][cc], Cp64[(size_t)k * CS + cl], dd);
                        double dv = fma(m2i64[cc], dd, es64[cc]) + Cq64[cl];
                        if (dv < d64) { d64 = dv; ci = cl; }   // ascending: first-min
                    }
                }
            } else if (best[cc] <= thr) {
                int c = bcode[cc];
                double dd = 0.0;
                #pragma unroll
                for (int k = 0; k < CD; ++k)
                    dd = fma(ze[k][cc], Cp64[(size_t)k * CS + c], dd);
                d64 = fma(m2i64[cc], dd, es64[cc]) + Cq64[c];
                ci = c;
            }
            // wave argmin butterfly (first-min tie-break)
            argmin_round_dpp<0xB1>(d64, ci);
            argmin_round_dpp<0x4E>(d64, ci);
            argmin_round_dpp<0x141>(d64, ci);
            argmin_round_dpp<0x140>(d64, ci);
            argmin_round_shfl(d64, ci, 16);
            argmin_round_shfl(d64, ci, 32);
            fcode[cc] = ci;
        }

        // ---- codes (lane 0, float2 per wave) ----
        if (l == 0) {
            float2 v = make_float2((float)fcode[0], (float)fcode[1]);
            *(float2*)&codes_out[((size_t)b * N + i) * T + tw] = v;
        }

        // ---- gather raw code + loss + straight-through (overwrites ze) ----
        const float* Cb = cb + (size_t)i * CS * CD;
        #pragma unroll
        for (int cc = 0; cc < CPW; ++cc) {
            int ui = __builtin_amdgcn_readfirstlane(fcode[cc]);
            const float* crow = Cb + (size_t)ui * CD;
            #pragma unroll
            for (int k = 0; k < CD; ++k) {
                double cv = (double)crow[k];
                double zv = ze[k][cc];
                double df = zv - cv;
                wloss = fma(df, df, wloss);
                ze[k][cc] = zv + (cv - zv);    // z_e + (z_q_i - z_e)
            }
        }

        // ---- out-proj (transposed weights, coalesced) + residual update ----
        const double* Wo = w_out_t + (size_t)i * CD * D;
        #pragma unroll 2
        for (int j = 0; j < 8; ++j) {
            int d = l + 64 * j;
            double wv[CD];
            #pragma unroll
            for (int k = 0; k < CD; ++k) wv[k] = Wo[(size_t)k * D + d];
            double bias = (double)out_b[i * D + d];
            #pragma unroll
            for (int cc = 0; cc < CPW; ++cc) {
                double o = 0.0;
                #pragma unroll
                for (int k = 0; k < CD; ++k) o = fma(wv[k], ze[k][cc], o);
                o += bias;
                r[cc][j] -= o;
            }
        }

        // ---- [F] single per-stage barrier: scan done + next-stage loads drained ----
        __syncthreads();
    }

    // ---- final: z_q = z - r, two d-halves via zt = bufB... use bufA overlay ----
    {
        float* zt2 = bufA;   // stage-8 scanned bufA? i=8 -> bufCur=bufA. Barrier passed; safe.
        const float* zb = z + (size_t)b * D * T + t0;
        float* ob = out + (size_t)b * D * T + t0;
        #pragma unroll
        for (int cc = 0; cc < CPW; ++cc)
            #pragma unroll
            for (int j = 0; j < 4; ++j)
                zt2[(l + 64 * j) * 17 + (w * CPW + cc)] = (float)r[cc][j];
        __syncthreads();
        #pragma unroll 2
        for (int rr = 0; rr < 8; ++rr) {
            int e = rr * 512 + tid;
            int d = e >> 4, c = e & 15;
            ob[(size_t)d * T + c] = zb[(size_t)d * T + c] - zt2[d * 17 + c];
        }
        __syncthreads();
        #pragma unroll
        for (int cc = 0; cc < CPW; ++cc)
            #pragma unroll
            for (int j = 4; j < 8; ++j)
                zt2[(l + 64 * (j - 4)) * 17 + (w * CPW + cc)] = (float)r[cc][j];
        __syncthreads();
        #pragma unroll 2
        for (int rr = 0; rr < 8; ++rr) {
            int e = rr * 512 + tid;
            int d = e >> 4, c = e & 15;
            ob[(size_t)(d + 256) * T + c] = zb[(size_t)(d + 256) * T + c] - zt2[d * 17 + c];
        }
    }

    // ---- per-block loss partial (wloss is wave-uniform) ----
    __syncthreads();
    if (l == 0) wl[w] = wloss;
    __syncthreads();
    if (tid == 0) {
        double s = 0.0;
        #pragma unroll
        for (int ww = 0; ww < 8; ++ww) s += wl[ww];
        wsl[blk] = s;
    }
}

__global__ void rvq_loss_reduce(const double* __restrict__ wsl,
                                float* __restrict__ out) {
    __shared__ double sm[4];
    int tid = threadIdx.x;
    double s = 0.0;
    for (int e = tid; e < NBLK; e += 256) s += wsl[e];
    for (int off = 32; off; off >>= 1) s += __shfl_xor(s, off, 64);
    if ((tid & 63) == 0) sm[tid >> 6] = s;
    __syncthreads();
    if (tid == 0) {
        double tot = ((sm[0] + sm[1]) + (sm[2] + sm[3])) * (1.0 / 262144.0);
        float* lossp = out + (size_t)B * D * T + (size_t)B * N * T + (size_t)B * N * CD * T;
        lossp[0] = (float)tot;   // commitment
        lossp[1] = (float)tot;   // codebook (identical in eval forward)
    }
}

extern "C" void kernel_launch(void* const* d_in, const int* in_sizes, int n_in,
                              void* d_out, int out_size, void* d_ws, size_t ws_size,
                              hipStream_t stream) {
    const float* z     = (const float*)d_in[0];
    const float* in_v  = (const float*)d_in[1];
    const float* in_g  = (const float*)d_in[2];
    const float* in_b  = (const float*)d_in[3];
    const float* out_v = (const float*)d_in[4];
    const float* out_g = (const float*)d_in[5];
    const float* out_b = (const float*)d_in[6];
    const float* cb    = (const float*)d_in[7];
    float* out  = (float*)d_out;
    double* ws  = (double*)d_ws;
    double* wsl = ws + 198144;   // loss partials

    rvq_prep<<<55, 256, 0, stream>>>(in_v, in_g, out_v, out_g, cb, ws);
    rvq_main<<<NBLK, 512, 73792, stream>>>(z, in_b, out_b, cb, ws, wsl, out);
    rvq_loss_reduce<<<1, 256, 0, stream>>>(wsl, out);
}